// Round 1
// baseline (166.660 us; speedup 1.0000x reference)
//
#include <hip/hip_runtime.h>

// Shapes (fixed per reference): N=512, IN1=IN2=KOUT=128
static constexpr int O1_ELEMS = 512*3*3*128*128;   // 75497472 floats
static constexpr int T_BYTES  = 1536*128*128*4;    // 100663296 bytes

// ---------------- Kernel A: out1[n,i,j,a,b] = x[n,i,a]*y[n,j,b] ----------------
__global__ __launch_bounds__(256) void out1_kernel(const float* __restrict__ x,
                                                   const float* __restrict__ y,
                                                   float* __restrict__ out1) {
    const int total4 = O1_ELEMS / 4;               // 18874368 float4 stores
    const float4* y4 = (const float4*)y;
    float4* o4 = (float4*)out1;
    for (int idx = blockIdx.x * 256 + threadIdx.x; idx < total4; idx += gridDim.x * 256) {
        int n   = idx / 36864;          // 9*4096 float4 per n
        int rem = idx - n * 36864;
        int ij  = rem >> 12;            // 0..8
        int r2  = rem & 4095;
        int a   = r2 >> 5;              // 0..127
        int b4  = r2 & 31;              // float4 index over b
        int i = ij / 3;
        int j = ij - 3 * i;
        float xs  = x[(n * 3 + i) * 128 + a];
        float4 yv = y4[(n * 3 + j) * 32 + b4];
        float4 r;
        r.x = xs * yv.x; r.y = xs * yv.y; r.z = xs * yv.z; r.w = xs * yv.w;
        o4[idx] = r;
    }
}

// ---------------- Kernel K1: t[m][a0][k] = sum_b y2[m][b] * w[a0][b][k] --------
// grid (12 m-tiles, 128 a), block 256. C-tile 128m x 128k, K=128 over b (BK=32).
__global__ __launch_bounds__(256) void k1_kernel(const float* __restrict__ y,
                                                 const float* __restrict__ w,
                                                 float* __restrict__ t) {
    __shared__ float As[128][33];   // y tile [m][b], +1 pad for broadcast reads
    __shared__ float Bs[32][128];   // w tile [b][k]
    const int mt = blockIdx.x;      // 0..11
    const int a0 = blockIdx.y;      // 0..127
    const int tid = threadIdx.x;
    const int tr = tid >> 4;        // 0..15 -> m rows tr*8..tr*8+7
    const int tc = tid & 15;        // 0..15 -> k cols tc*4..+3 and 64+tc*4..+3
    const float* wa = w + (size_t)a0 * 16384;

    float acc[8][8] = {};

    for (int b0 = 0; b0 < 128; b0 += 32) {
        // load A: 128 x 32 floats, coalesced along b
        {
            int bcol = tid & 31, mrow = tid >> 5;    // 8 rows/pass
            #pragma unroll
            for (int mm = 0; mm < 128; mm += 8)
                As[mm + mrow][bcol] = y[(size_t)(mt * 128 + mm + mrow) * 128 + b0 + bcol];
        }
        // load B: 32 x 128 floats, coalesced float4 along k
        {
            int k4 = tid & 31, bb0 = tid >> 5;       // 8 b-rows/pass
            #pragma unroll
            for (int bb = 0; bb < 32; bb += 8) {
                float4 v = ((const float4*)(wa + (size_t)(b0 + bb + bb0) * 128))[k4];
                *((float4*)&Bs[bb + bb0][k4 * 4]) = v;
            }
        }
        __syncthreads();
        #pragma unroll
        for (int b = 0; b < 32; ++b) {
            float av[8], bv[8];
            #pragma unroll
            for (int q = 0; q < 8; ++q) av[q] = As[tr * 8 + q][b];
            float4 blo = *((const float4*)&Bs[b][tc * 4]);
            float4 bhi = *((const float4*)&Bs[b][64 + tc * 4]);
            bv[0] = blo.x; bv[1] = blo.y; bv[2] = blo.z; bv[3] = blo.w;
            bv[4] = bhi.x; bv[5] = bhi.y; bv[6] = bhi.z; bv[7] = bhi.w;
            #pragma unroll
            for (int q = 0; q < 8; ++q)
                #pragma unroll
                for (int r = 0; r < 8; ++r) acc[q][r] += av[q] * bv[r];
        }
        __syncthreads();
    }
    // write t[m][a0][k]
    #pragma unroll
    for (int q = 0; q < 8; ++q) {
        int m = mt * 128 + tr * 8 + q;
        float* dst = t + ((size_t)m * 128 + a0) * 128;
        float4 lo = {acc[q][0], acc[q][1], acc[q][2], acc[q][3]};
        float4 hi = {acc[q][4], acc[q][5], acc[q][6], acc[q][7]};
        *((float4*)(dst + tc * 4)) = lo;
        *((float4*)(dst + 64 + tc * 4)) = hi;
    }
}

// ---------------- Kernel K2: out2[n,i,j,k] = 0.75*a * sum_a x[n,i,a]*t[m][a][k] -
// block per (n,j), 384 threads = (i,k)
__global__ __launch_bounds__(384) void k2_kernel(const float* __restrict__ x,
                                                 const float* __restrict__ a_s,
                                                 const float* __restrict__ t,
                                                 float* __restrict__ out2) {
    __shared__ float tl[16384];     // t[m] tile [a][k]  (64 KB)
    __shared__ float xl[384];       // x[n] (3 x 128)
    const int n = blockIdx.x / 3;
    const int j = blockIdx.x - 3 * n;
    const float* tm = t + (size_t)(n * 3 + j) * 16384;
    const float4* t4 = (const float4*)tm;
    float4* tl4 = (float4*)tl;
    for (int idx = threadIdx.x; idx < 4096; idx += 384) tl4[idx] = t4[idx];
    if (threadIdx.x < 384) xl[threadIdx.x] = x[(size_t)n * 384 + threadIdx.x];
    __syncthreads();
    const int i = threadIdx.x >> 7;      // 0..2
    const int k = threadIdx.x & 127;
    float acc = 0.f;
    #pragma unroll 8
    for (int a = 0; a < 128; ++a)
        acc += xl[i * 128 + a] * tl[a * 128 + k];
    out2[((size_t)(n * 3 + i) * 3 + j) * 128 + k] = 0.75f * a_s[0] * acc;
}

extern "C" void kernel_launch(void* const* d_in, const int* in_sizes, int n_in,
                              void* d_out, int out_size, void* d_ws, size_t ws_size,
                              hipStream_t stream) {
    const float* w  = (const float*)d_in[0];
    const float* as = (const float*)d_in[1];
    const float* x  = (const float*)d_in[2];
    const float* y  = (const float*)d_in[3];
    float* out1 = (float*)d_out;
    float* out2 = out1 + O1_ELEMS;

    // t scratch (100 MB): prefer d_ws; else reuse the out1 region (overwritten
    // afterwards by out1_kernel — stream-ordered, deterministic).
    float* t = (ws_size >= (size_t)T_BYTES) ? (float*)d_ws : out1;

    k1_kernel<<<dim3(12, 128), 256, 0, stream>>>(y, w, t);
    k2_kernel<<<1536, 384, 0, stream>>>(x, as, t, out2);
    out1_kernel<<<4096, 256, 0, stream>>>(x, y, out1);
}

// Round 3
// 138.664 us; speedup vs baseline: 1.2019x; 1.2019x over previous
//
#include <hip/hip_runtime.h>
#include <stdint.h>

typedef __attribute__((ext_vector_type(8))) short bf16x8;
typedef __attribute__((ext_vector_type(4))) float f32x4;

static constexpr int O1_ELEMS = 512*3*3*128*128;      // 75497472 floats
static constexpr size_t WB2_BYTES = 128u*128*128*2;   // 4 MB  (wb2[a][k][b] bf16)
static constexpr size_t YB_BYTES  = 1536u*128*2;      // 384 KB (yb[m][b] bf16)
static constexpr size_t SCRATCH_BYTES = WB2_BYTES + YB_BYTES;

__device__ inline unsigned short f32_to_bf16(float f) {
    union { float f; uint32_t u; } v; v.f = f;
    uint32_t r = v.u + 0x7FFF + ((v.u >> 16) & 1);    // RNE
    return (unsigned short)(r >> 16);
}

__device__ inline void gload_lds16(const void* g, void* l) {
    __builtin_amdgcn_global_load_lds(
        (const __attribute__((address_space(1))) uint32_t*)g,
        (__attribute__((address_space(3))) uint32_t*)l, 16, 0, 0);
}

// ---- conv: wb2[a][k][b] = bf16(w[a][b][k]);  yb[m][b] = bf16(y[m][b]) ----
__global__ __launch_bounds__(256) void conv_kernel(const float* __restrict__ w,
                                                   const float* __restrict__ y,
                                                   unsigned short* __restrict__ wb2,
                                                   unsigned short* __restrict__ yb) {
    if (blockIdx.x < 128) {
        __shared__ unsigned short lt[128][132];        // [b][k], pad to 132
        const int a = blockIdx.x;
        const int t = threadIdx.x;
        const float4* src = (const float4*)(w + (size_t)a * 16384);
        #pragma unroll
        for (int it = 0; it < 16; ++it) {              // 16*256 = 4096 float4 = 128x128 f32
            int fidx = it * 256 + t;
            float4 v = src[fidx];
            int b = fidx >> 5, k4 = fidx & 31;
            unsigned short* d = &lt[b][k4 * 4];
            d[0] = f32_to_bf16(v.x); d[1] = f32_to_bf16(v.y);
            d[2] = f32_to_bf16(v.z); d[3] = f32_to_bf16(v.w);
        }
        __syncthreads();
        const int k = t >> 1, bh = t & 1;
        uint4* dst = (uint4*)(wb2 + (size_t)a * 16384 + (size_t)k * 128 + bh * 64);
        #pragma unroll
        for (int i8 = 0; i8 < 8; ++i8) {
            uint32_t pk[4];
            #pragma unroll
            for (int q = 0; q < 4; ++q) {
                uint32_t lo = lt[bh * 64 + i8 * 8 + q * 2][k];
                uint32_t hi = lt[bh * 64 + i8 * 8 + q * 2 + 1][k];
                pk[q] = lo | (hi << 16);
            }
            uint4 vv = {pk[0], pk[1], pk[2], pk[3]};
            dst[i8] = vv;
        }
    } else {
        const int bid = blockIdx.x - 128;              // 0..3
        const float4* ys = (const float4*)y;
        for (int idx = bid * 256 + threadIdx.x; idx < 49152; idx += 1024) {
            float4 v = ys[idx];
            unsigned short s[4] = {f32_to_bf16(v.x), f32_to_bf16(v.y),
                                   f32_to_bf16(v.z), f32_to_bf16(v.w)};
            uint2 pk = {(uint32_t)s[0] | ((uint32_t)s[1] << 16),
                        (uint32_t)s[2] | ((uint32_t)s[3] << 16)};
            ((uint2*)yb)[idx] = pk;
        }
    }
}

// ---- mega: blocks [0,ncomp): fused out2; blocks [ncomp,grid): out1 stream ----
__global__ __launch_bounds__(256) void mega_kernel(const float* __restrict__ x,
                                                   const float* __restrict__ y,
                                                   const float* __restrict__ a_s,
                                                   const unsigned short* __restrict__ wb2,
                                                   const unsigned short* __restrict__ yb,
                                                   float* __restrict__ out1,
                                                   float* __restrict__ out2,
                                                   int ncomp) {
    if ((int)blockIdx.x >= ncomp) {
        const int nblk = gridDim.x - ncomp;
        const int total4 = O1_ELEMS / 4;
        const float4* y4 = (const float4*)y;
        float4* o4 = (float4*)out1;
        for (int idx = (blockIdx.x - ncomp) * 256 + threadIdx.x; idx < total4;
             idx += nblk * 256) {
            int n   = idx / 36864;
            int rem = idx - n * 36864;
            int ij  = rem >> 12;
            int r2  = rem & 4095;
            int aa  = r2 >> 5;
            int b4  = r2 & 31;
            int i = ij / 3, j = ij - 3 * i;
            float  xs1 = x[(n * 3 + i) * 128 + aa];
            float4 yv  = y4[(n * 3 + j) * 32 + b4];
            float4 r; r.x = xs1 * yv.x; r.y = xs1 * yv.y; r.z = xs1 * yv.z; r.w = xs1 * yv.w;
            o4[idx] = r;
        }
        return;
    }

    // ---------------- compute block: out2 tile [mt*32..+32) x [kt*64..+64) ---
    __shared__ __align__(16) unsigned short Bs[2][8192];  // [buf][64k][128b] bf16
    __shared__ __align__(16) float xsh[2][16][3][32];     // [buf][ac][i][m']
    const int tid = threadIdx.x;
    const int l   = tid & 63;
    const int wv  = tid >> 6;        // wave 0..3 -> k-cols [wv*16, wv*16+16)
    const int mt  = blockIdx.x >> 1; // 0..47
    const int kt  = blockIdx.x & 1;  // 0..1
    const int l15 = l & 15, lg = l >> 4;

    // A-frags (Y) straight from global, held for the whole a-loop.
    // A[row=m][k=b]: row = l15, elems j: b = ks*32 + lg*8 + j  (16B contiguous)
    bf16x8 afrag[2][4];
    #pragma unroll
    for (int Mt = 0; Mt < 2; ++Mt)
        #pragma unroll
        for (int ks = 0; ks < 4; ++ks)
            afrag[Mt][ks] = *(const bf16x8*)(yb + (size_t)(mt * 32 + Mt * 16 + l15) * 128
                                              + ks * 32 + lg * 8);

    // x chunk 0 -> regs
    float xreg[6];
    #pragma unroll
    for (int p = 0; p < 6; ++p) {
        int e = tid + p * 256;
        int ac = e / 96, r = e - ac * 96, i = r >> 5, mm = r & 31;
        int n = (mt * 32 + mm) / 3;
        xreg[p] = x[n * 384 + i * 128 + ac];
    }
    // stage B(a=0) -> Bs[0]
    {
        const char* src = (const char*)wb2 + (size_t)kt * 16384;
        #pragma unroll
        for (int p = 0; p < 4; ++p)
            gload_lds16(src + p * 4096 + wv * 1024 + l * 16,
                        (char*)&Bs[0][0] + p * 4096 + wv * 1024);
    }
    // xreg chunk0 -> xsh[0]
    #pragma unroll
    for (int p = 0; p < 6; ++p)
        ((float*)&xsh[0][0][0][0])[tid + p * 256] = xreg[p];
    __syncthreads();

    float acc2[3][2][4] = {};

    for (int a = 0; a < 128; ++a) {
        const int buf = a & 1;
        if (a < 127) {  // prefetch B(a+1)
            const char* src = (const char*)wb2 + (size_t)(a + 1) * 32768 + (size_t)kt * 16384;
            #pragma unroll
            for (int p = 0; p < 4; ++p)
                gload_lds16(src + p * 4096 + wv * 1024 + l * 16,
                            (char*)&Bs[buf ^ 1][0] + p * 4096 + wv * 1024);
        }
        if ((a & 15) == 0 && a + 16 < 128) {  // prefetch next x chunk -> regs
            const int c1b = ((a >> 4) + 1) * 16;
            #pragma unroll
            for (int p = 0; p < 6; ++p) {
                int e = tid + p * 256;
                int ac = e / 96, r = e - ac * 96, i = r >> 5, mm = r & 31;
                int n = (mt * 32 + mm) / 3;
                xreg[p] = x[n * 384 + i * 128 + c1b + ac];
            }
        }

        // t_a tile via MFMA:  t[m][k] = sum_b Y[m][b] * W_a[b][k]
        f32x4 tA0 = {0.f, 0.f, 0.f, 0.f}, tA1 = {0.f, 0.f, 0.f, 0.f};
        #pragma unroll
        for (int ks = 0; ks < 4; ++ks) {
            // B[k(b)][col=k']: col = wv*16+l15 (LDS row), elems: 8 consecutive b
            bf16x8 bfrag = *(const bf16x8*)&Bs[buf][(size_t)(wv * 16 + l15) * 128
                                                   + ks * 32 + lg * 8];
            tA0 = __builtin_amdgcn_mfma_f32_16x16x32_bf16(afrag[0][ks], bfrag, tA0, 0, 0, 0);
            tA1 = __builtin_amdgcn_mfma_f32_16x16x32_bf16(afrag[1][ks], bfrag, tA1, 0, 0, 0);
        }

        // epilogue: out2acc[i][Mt][r] += x[n(m),i,a] * t_a[m][k]
        {
            const int ac = a & 15, xb = (a >> 4) & 1;
            #pragma unroll
            for (int i = 0; i < 3; ++i) {
                float4 xv0 = *(const float4*)&xsh[xb][ac][i][0 * 16 + lg * 4];
                float4 xv1 = *(const float4*)&xsh[xb][ac][i][1 * 16 + lg * 4];
                acc2[i][0][0] += xv0.x * tA0[0]; acc2[i][0][1] += xv0.y * tA0[1];
                acc2[i][0][2] += xv0.z * tA0[2]; acc2[i][0][3] += xv0.w * tA0[3];
                acc2[i][1][0] += xv1.x * tA1[0]; acc2[i][1][1] += xv1.y * tA1[1];
                acc2[i][1][2] += xv1.z * tA1[2]; acc2[i][1][3] += xv1.w * tA1[3];
            }
        }
        if ((a & 15) == 15 && a < 127) {  // commit next x chunk to LDS
            const int nb = ((a >> 4) + 1) & 1;
            #pragma unroll
            for (int p = 0; p < 6; ++p)
                ((float*)&xsh[nb][0][0][0])[tid + p * 256] = xreg[p];
        }
        __syncthreads();
    }

    const float alpha = 0.75f * a_s[0];
    const int kcol = kt * 64 + wv * 16 + l15;
    #pragma unroll
    for (int i = 0; i < 3; ++i)
        #pragma unroll
        for (int Mt = 0; Mt < 2; ++Mt)
            #pragma unroll
            for (int r = 0; r < 4; ++r) {
                int m = mt * 32 + Mt * 16 + lg * 4 + r;
                int n = m / 3, j = m - 3 * n;
                out2[((size_t)(n * 3 + i) * 3 + j) * 128 + kcol] = alpha * acc2[i][Mt][r];
            }
}

extern "C" void kernel_launch(void* const* d_in, const int* in_sizes, int n_in,
                              void* d_out, int out_size, void* d_ws, size_t ws_size,
                              hipStream_t stream) {
    const float* w  = (const float*)d_in[0];
    const float* as = (const float*)d_in[1];
    const float* x  = (const float*)d_in[2];
    const float* y  = (const float*)d_in[3];
    float* out1 = (float*)d_out;
    float* out2 = out1 + O1_ELEMS;

    const bool have_ws = (ws_size >= SCRATCH_BYTES);
    char* scratch = have_ws ? (char*)d_ws : (char*)d_out;  // fallback: out1 head, sequential
    unsigned short* wb2 = (unsigned short*)scratch;
    unsigned short* yb  = (unsigned short*)(scratch + WB2_BYTES);

    conv_kernel<<<132, 256, 0, stream>>>(w, y, wb2, yb);

    if (have_ws) {
        // one mega launch: 96 compute blocks + 4096 out1-stream blocks, overlapped
        mega_kernel<<<96 + 4096, 256, 0, stream>>>(x, y, as, wb2, yb, out1, out2, 96);
    } else {
        // scratch lives in the out1 region: compute first, then stream out1 over it
        mega_kernel<<<96, 256, 0, stream>>>(x, y, as, wb2, yb, out1, out2, 96);
        mega_kernel<<<4096, 256, 0, stream>>>(x, y, as, wb2, yb, out1, out2, 0);
    }
}

// Round 5
// 119.912 us; speedup vs baseline: 1.3898x; 1.1564x over previous
//
#include <hip/hip_runtime.h>
#include <stdint.h>

typedef __attribute__((ext_vector_type(8))) short bf16x8;
typedef __attribute__((ext_vector_type(4))) float f32x4;

static constexpr int O1_ELEMS   = 512*3*3*128*128;    // 75497472 floats
static constexpr int WB2_FLOATS = 1048576;            // 4 MB bf16 wb2[a][k][b]
static constexpr int SKIP4      = WB2_FLOATS / 4;     // 262144 float4s (scratch head)
static constexpr int TOTAL4     = O1_ELEMS / 4;       // 18874368
static constexpr int NCOMP      = 96;                 // 48 mt x 2 kt
static constexpr int NSTREAM    = 4096;

__device__ inline unsigned short f32_to_bf16(float f) {
    union { float f; uint32_t u; } v; v.f = f;
    uint32_t r = v.u + 0x7FFF + ((v.u >> 16) & 1);    // RNE
    return (unsigned short)(r >> 16);
}

__device__ inline bf16x8 bf16x8_from_f32(const float* p) {
    float4 v0 = *(const float4*)p;
    float4 v1 = *(const float4*)(p + 4);
    union { bf16x8 v; unsigned short s[8]; } u;
    u.s[0] = f32_to_bf16(v0.x); u.s[1] = f32_to_bf16(v0.y);
    u.s[2] = f32_to_bf16(v0.z); u.s[3] = f32_to_bf16(v0.w);
    u.s[4] = f32_to_bf16(v1.x); u.s[5] = f32_to_bf16(v1.y);
    u.s[6] = f32_to_bf16(v1.z); u.s[7] = f32_to_bf16(v1.w);
    return u.v;
}

// ---- conv: wb2[a][k][b] = bf16(w[a][b][k]) (wb2 lives at out1 head) ----
__global__ __launch_bounds__(256) void conv_kernel(const float* __restrict__ w,
                                                   unsigned short* __restrict__ wb2) {
    __shared__ unsigned short lt[128][132];
    const int a = blockIdx.x;
    const int t = threadIdx.x;
    const float4* src = (const float4*)(w + (size_t)a * 16384);
    #pragma unroll
    for (int it = 0; it < 16; ++it) {                  // 4096 float4 = 128x128 f32
        int fidx = it * 256 + t;
        float4 v = src[fidx];
        int b = fidx >> 5, k4 = fidx & 31;
        unsigned short* d = &lt[b][k4 * 4];
        d[0] = f32_to_bf16(v.x); d[1] = f32_to_bf16(v.y);
        d[2] = f32_to_bf16(v.z); d[3] = f32_to_bf16(v.w);
    }
    __syncthreads();
    const int k = t >> 1, bh = t & 1;
    uint4* dst = (uint4*)(wb2 + (size_t)a * 16384 + (size_t)k * 128 + bh * 64);
    #pragma unroll
    for (int i8 = 0; i8 < 8; ++i8) {
        uint32_t pk[4];
        #pragma unroll
        for (int q = 0; q < 4; ++q) {
            uint32_t lo = lt[bh * 64 + i8 * 8 + q * 2][k];
            uint32_t hi = lt[bh * 64 + i8 * 8 + q * 2 + 1][k];
            pk[q] = lo | (hi << 16);
        }
        uint4 vv = {pk[0], pk[1], pk[2], pk[3]};
        dst[i8] = vv;
    }
}

// ---- mega: [0,NCOMP) fused out2 (all 128 a); [NCOMP,..) stream out1 tail ----
__global__ __launch_bounds__(256) void mega_kernel(const float* __restrict__ x,
                                                   const float* __restrict__ y,
                                                   const float* __restrict__ a_s,
                                                   const unsigned short* __restrict__ wb2,
                                                   float* __restrict__ out1,
                                                   float* __restrict__ out2) {
    if ((int)blockIdx.x >= NCOMP) {
        const float4* y4 = (const float4*)y;
        float4* o4 = (float4*)out1;
        for (int idx = SKIP4 + ((int)blockIdx.x - NCOMP) * 256 + (int)threadIdx.x;
             idx < TOTAL4; idx += NSTREAM * 256) {
            int n   = idx / 36864;
            int rem = idx - n * 36864;
            int ij  = rem >> 12;
            int r2  = rem & 4095;
            int aa  = r2 >> 5;
            int b4  = r2 & 31;
            int i = ij / 3, j = ij - 3 * i;
            float  xs1 = x[(n * 3 + i) * 128 + aa];
            float4 yv  = y4[(n * 3 + j) * 32 + b4];
            float4 r; r.x = xs1 * yv.x; r.y = xs1 * yv.y; r.z = xs1 * yv.z; r.w = xs1 * yv.w;
            o4[idx] = r;
        }
        return;
    }

    // compute block: out2 tile [mt*32..+32)m x [kt*64..+64)k, all a
    __shared__ float xsh[32][3][32];       // [ac][i][m']  12 KB, per 32-a chunk
    const int bid  = blockIdx.x;
    const int kt   = bid & 1;
    const int mt   = bid >> 1;             // 0..47
    const int tid  = threadIdx.x;
    const int l    = tid & 63;
    const int wv   = tid >> 6;             // wave -> k-cols [wv*16, +16)
    const int l15  = l & 15, lg = l >> 4;

    // A-frags (Y, bf16 cvt in-reg): row m = mt*32+Mt*16+l15, elems b = ks*32+lg*8..
    bf16x8 afrag[2][4];
    #pragma unroll
    for (int Mt = 0; Mt < 2; ++Mt)
        #pragma unroll
        for (int ks = 0; ks < 4; ++ks)
            afrag[Mt][ks] = bf16x8_from_f32(
                y + (size_t)(mt * 32 + Mt * 16 + l15) * 128 + ks * 32 + lg * 8);

    float acc2[3][2][4] = {};
    const unsigned short* wbase =
        wb2 + (size_t)(kt * 64 + wv * 16 + l15) * 128 + lg * 8;

    for (int seg = 0; seg < 4; ++seg) {
        __syncthreads();
        // x tile for this 32-a chunk: 32a x 3i x 32m = 3072 floats
        #pragma unroll
        for (int p = 0; p < 12; ++p) {
            int e = tid + p * 256;
            int ac = e / 96, r = e - ac * 96, i = r >> 5, mm = r & 31;
            int n = (mt * 32 + mm) / 3;
            xsh[ac][i][mm] = x[n * 384 + i * 128 + seg * 32 + ac];
        }
        __syncthreads();

        #pragma unroll 2
        for (int ac = 0; ac < 32; ++ac) {
            const int a = seg * 32 + ac;
            const unsigned short* wp = wbase + (size_t)a * 16384;
            bf16x8 bf0 = *(const bf16x8*)(wp);
            bf16x8 bf1 = *(const bf16x8*)(wp + 32);
            bf16x8 bf2 = *(const bf16x8*)(wp + 64);
            bf16x8 bf3 = *(const bf16x8*)(wp + 96);

            f32x4 t0 = {0.f, 0.f, 0.f, 0.f}, t1 = {0.f, 0.f, 0.f, 0.f};
            t0 = __builtin_amdgcn_mfma_f32_16x16x32_bf16(afrag[0][0], bf0, t0, 0, 0, 0);
            t1 = __builtin_amdgcn_mfma_f32_16x16x32_bf16(afrag[1][0], bf0, t1, 0, 0, 0);
            t0 = __builtin_amdgcn_mfma_f32_16x16x32_bf16(afrag[0][1], bf1, t0, 0, 0, 0);
            t1 = __builtin_amdgcn_mfma_f32_16x16x32_bf16(afrag[1][1], bf1, t1, 0, 0, 0);
            t0 = __builtin_amdgcn_mfma_f32_16x16x32_bf16(afrag[0][2], bf2, t0, 0, 0, 0);
            t1 = __builtin_amdgcn_mfma_f32_16x16x32_bf16(afrag[1][2], bf2, t1, 0, 0, 0);
            t0 = __builtin_amdgcn_mfma_f32_16x16x32_bf16(afrag[0][3], bf3, t0, 0, 0, 0);
            t1 = __builtin_amdgcn_mfma_f32_16x16x32_bf16(afrag[1][3], bf3, t1, 0, 0, 0);

            #pragma unroll
            for (int i = 0; i < 3; ++i) {
                float4 xv0 = *(const float4*)&xsh[ac][i][lg * 4];
                float4 xv1 = *(const float4*)&xsh[ac][i][16 + lg * 4];
                acc2[i][0][0] += xv0.x * t0[0]; acc2[i][0][1] += xv0.y * t0[1];
                acc2[i][0][2] += xv0.z * t0[2]; acc2[i][0][3] += xv0.w * t0[3];
                acc2[i][1][0] += xv1.x * t1[0]; acc2[i][1][1] += xv1.y * t1[1];
                acc2[i][1][2] += xv1.z * t1[2]; acc2[i][1][3] += xv1.w * t1[3];
            }
        }
    }

    const float alpha = 0.75f * a_s[0];
    const int kcol = kt * 64 + wv * 16 + l15;
    #pragma unroll
    for (int i = 0; i < 3; ++i)
        #pragma unroll
        for (int Mt = 0; Mt < 2; ++Mt)
            #pragma unroll
            for (int r = 0; r < 4; ++r) {
                int m = mt * 32 + Mt * 16 + lg * 4 + r;
                int n = m / 3, j = m - 3 * n;
                out2[((size_t)(n * 3 + i) * 3 + j) * 128 + kcol] = alpha * acc2[i][Mt][r];
            }
}

// ---- finish: rewrite out1 head (the wb2 scratch region) with true out1 ----
__global__ __launch_bounds__(256) void finish_kernel(const float* __restrict__ x,
                                                     const float* __restrict__ y,
                                                     float* __restrict__ out1) {
    const float4* y4 = (const float4*)y;
    float4* o4 = (float4*)out1;
    for (int idx = (int)blockIdx.x * 256 + (int)threadIdx.x; idx < SKIP4;
         idx += 256 * 256) {
        int n   = idx / 36864;
        int rem = idx - n * 36864;
        int ij  = rem >> 12;
        int r2  = rem & 4095;
        int aa  = r2 >> 5;
        int b4  = r2 & 31;
        int i = ij / 3, j = ij - 3 * i;
        float  xs1 = x[(n * 3 + i) * 128 + aa];
        float4 yv  = y4[(n * 3 + j) * 32 + b4];
        float4 r; r.x = xs1 * yv.x; r.y = xs1 * yv.y; r.z = xs1 * yv.z; r.w = xs1 * yv.w;
        o4[idx] = r;
    }
}

extern "C" void kernel_launch(void* const* d_in, const int* in_sizes, int n_in,
                              void* d_out, int out_size, void* d_ws, size_t ws_size,
                              hipStream_t stream) {
    const float* w  = (const float*)d_in[0];
    const float* as = (const float*)d_in[1];
    const float* x  = (const float*)d_in[2];
    const float* y  = (const float*)d_in[3];
    float* out1 = (float*)d_out;
    float* out2 = out1 + O1_ELEMS;

    // wb2 scratch at out1 head (rewritten by finish): no ws dependency
    unsigned short* wb2 = (unsigned short*)out1;

    conv_kernel<<<128, 256, 0, stream>>>(w, wb2);
    mega_kernel<<<NCOMP + NSTREAM, 256, 0, stream>>>(x, y, as, wb2, out1, out2);
    finish_kernel<<<256, 256, 0, stream>>>(x, y, out1);
}